// Round 1
// baseline (2043.350 us; speedup 1.0000x reference)
//
#include <hip/hip_runtime.h>
#include <cstddef>
#include <cstdint>

#define NNODES 100000
#define NEDGES 800000

// ---------------------------------------------------------------------------
// zero-fill (avoids hipMemsetAsync under graph capture)
// ---------------------------------------------------------------------------
__global__ __launch_bounds__(256) void zero_kernel(float4* __restrict__ p, int n4) {
    int i = blockIdx.x * blockDim.x + threadIdx.x;
    const int stride = gridDim.x * blockDim.x;
    for (; i < n4; i += stride) p[i] = make_float4(0.f, 0.f, 0.f, 0.f);
}

// ---------------------------------------------------------------------------
// out[N,DO] = relu( A@WA (+ B@WB) + bias )   K=128 fixed
// block = 256 threads as 16(ty) x 16(tx); each thread: 4 rows x (DO/16) cols
// W chunks staged in LDS, 32 k at a time.
// ---------------------------------------------------------------------------
template<int DO, bool DUAL>
__global__ __launch_bounds__(256) void gemm_kernel(
    const float* __restrict__ A,
    const float* __restrict__ B,
    const float* __restrict__ WA,
    const float* __restrict__ WB,
    const float* __restrict__ bias,
    float* __restrict__ out,
    int N)
{
    constexpr int CPT = DO / 16;       // cols per thread (8 or 4)
    constexpr int KCHUNK = 32;
    constexpr int NW = DUAL ? 2 : 1;
    __shared__ float sW[NW * KCHUNK * DO];

    const int tid = threadIdx.x;
    const int tx = tid & 15;
    const int ty = tid >> 4;
    const int row0 = blockIdx.x * 64 + ty * 4;

    float acc[4][CPT];
#pragma unroll
    for (int r = 0; r < 4; ++r)
#pragma unroll
        for (int c = 0; c < CPT; ++c) acc[r][c] = 0.f;

    int rowc[4];
#pragma unroll
    for (int r = 0; r < 4; ++r) rowc[r] = min(row0 + r, N - 1);

    for (int k0 = 0; k0 < 128; k0 += KCHUNK) {
        const int total = KCHUNK * DO;            // 4096 (DO=128) or 2048 (DO=64)
        for (int i = tid * 4; i < total; i += 256 * 4) {
            *(float4*)&sW[i] = *(const float4*)&WA[k0 * DO + i];
            if constexpr (DUAL)
                *(float4*)&sW[KCHUNK * DO + i] = *(const float4*)&WB[k0 * DO + i];
        }
        __syncthreads();

#pragma unroll 2
        for (int kk = 0; kk < KCHUNK; kk += 4) {
            float4 av[4], bv[4];
#pragma unroll
            for (int r = 0; r < 4; ++r) {
                av[r] = *(const float4*)&A[(size_t)rowc[r] * 128 + k0 + kk];
                if constexpr (DUAL)
                    bv[r] = *(const float4*)&B[(size_t)rowc[r] * 128 + k0 + kk];
            }
#pragma unroll
            for (int j = 0; j < 4; ++j) {
                float wa[CPT];
#pragma unroll
                for (int c = 0; c < CPT; c += 4) {
                    float4 w4 = *(const float4*)&sW[(kk + j) * DO + tx * CPT + c];
                    wa[c] = w4.x; wa[c + 1] = w4.y; wa[c + 2] = w4.z; wa[c + 3] = w4.w;
                }
#pragma unroll
                for (int r = 0; r < 4; ++r) {
                    const float a = (j == 0) ? av[r].x : (j == 1) ? av[r].y
                                  : (j == 2) ? av[r].z : av[r].w;
#pragma unroll
                    for (int c = 0; c < CPT; ++c) acc[r][c] += a * wa[c];
                }
                if constexpr (DUAL) {
                    float wb[CPT];
#pragma unroll
                    for (int c = 0; c < CPT; c += 4) {
                        float4 w4 = *(const float4*)&sW[KCHUNK * DO + (kk + j) * DO + tx * CPT + c];
                        wb[c] = w4.x; wb[c + 1] = w4.y; wb[c + 2] = w4.z; wb[c + 3] = w4.w;
                    }
#pragma unroll
                    for (int r = 0; r < 4; ++r) {
                        const float b = (j == 0) ? bv[r].x : (j == 1) ? bv[r].y
                                      : (j == 2) ? bv[r].z : bv[r].w;
#pragma unroll
                        for (int c = 0; c < CPT; ++c) acc[r][c] += b * wb[c];
                    }
                }
            }
        }
        __syncthreads();
    }

#pragma unroll
    for (int r = 0; r < 4; ++r) {
        const int row = row0 + r;
        if (row < N) {
#pragma unroll
            for (int c = 0; c < CPT; c += 4) {
                float4 o;
                o.x = fmaxf(acc[r][c + 0] + bias[tx * CPT + c + 0], 0.f);
                o.y = fmaxf(acc[r][c + 1] + bias[tx * CPT + c + 1], 0.f);
                o.z = fmaxf(acc[r][c + 2] + bias[tx * CPT + c + 2], 0.f);
                o.w = fmaxf(acc[r][c + 3] + bias[tx * CPT + c + 3], 0.f);
                *(float4*)&out[(size_t)row * DO + tx * CPT + c] = o;
            }
        }
    }
}

// ---------------------------------------------------------------------------
// scatter-max: one wave per edge, lane handles 2 floats of the 128-wide row.
// Messages are post-ReLU (>=0), so int atomicMax on the bit pattern is exact
// and init-0 reproduces segment_max + isfinite-replacement semantics.
// ---------------------------------------------------------------------------
__global__ __launch_bounds__(256) void scatter_max_kernel(
    const float* __restrict__ m,
    const int* __restrict__ src,
    const int* __restrict__ dst,
    float* __restrict__ agg,
    int E)
{
    const int lane = threadIdx.x & 63;
    const int wave = (blockIdx.x * blockDim.x + threadIdx.x) >> 6;
    const int nwaves = (gridDim.x * blockDim.x) >> 6;
    for (int e = wave; e < E; e += nwaves) {
        const int s = src[e];
        const int d = dst[e];
        const float2 v = *(const float2*)&m[(size_t)s * 128 + lane * 2];
        int* ap = (int*)&agg[(size_t)d * 128 + lane * 2];
        atomicMax(ap,     __float_as_int(v.x));
        atomicMax(ap + 1, __float_as_int(v.y));
    }
}

// ---------------------------------------------------------------------------
// row-wise log_softmax over 64 classes: one wave per row, lane = col.
// ---------------------------------------------------------------------------
__global__ __launch_bounds__(256) void logsoftmax_kernel(
    const float* __restrict__ in, float* __restrict__ out, int N)
{
    const int lane = threadIdx.x & 63;
    const int row = blockIdx.x * 4 + (threadIdx.x >> 6);
    if (row >= N) return;
    float v = in[(size_t)row * 64 + lane];
    float mx = v;
#pragma unroll
    for (int off = 32; off > 0; off >>= 1) mx = fmaxf(mx, __shfl_xor(mx, off));
    float e = __expf(v - mx);
    float s = e;
#pragma unroll
    for (int off = 32; off > 0; off >>= 1) s += __shfl_xor(s, off);
    out[(size_t)row * 64 + lane] = v - mx - __logf(s);
}

// ---------------------------------------------------------------------------
extern "C" void kernel_launch(void* const* d_in, const int* in_sizes, int n_in,
                              void* d_out, int out_size, void* d_ws, size_t ws_size,
                              hipStream_t stream)
{
    const int N = NNODES, E = NEDGES;
    const float* x  = (const float*)d_in[0];
    const int* esrc = (const int*)d_in[1];
    const int* edst = (const int*)d_in[2];
    const float* Wp[3] = {(const float*)d_in[3], (const float*)d_in[8],  (const float*)d_in[13]};
    const float* bp[3] = {(const float*)d_in[4], (const float*)d_in[9],  (const float*)d_in[14]};
    const float* Ws[3] = {(const float*)d_in[5], (const float*)d_in[10], (const float*)d_in[15]};
    const float* Wn[3] = {(const float*)d_in[6], (const float*)d_in[11], (const float*)d_in[16]};
    const float* bn[3] = {(const float*)d_in[7], (const float*)d_in[12], (const float*)d_in[17]};

    float* bufA = (float*)d_ws;                 // N*128 f32
    float* bufB = bufA + (size_t)N * 128;       // N*128 f32
    float* bufC = bufB + (size_t)N * 128;       // N*128 f32 (agg)

    const int gblocks = (N + 63) / 64;          // 1563
    const int zblocks = 2048;
    const int n4 = N * 128 / 4;
    dim3 blk(256);

    // ---- layer 0 (input = x)
    gemm_kernel<128, false><<<gblocks, blk, 0, stream>>>(x, nullptr, Wp[0], nullptr, bp[0], bufB, N);
    zero_kernel<<<zblocks, blk, 0, stream>>>((float4*)bufC, n4);
    scatter_max_kernel<<<2048, blk, 0, stream>>>(bufB, esrc, edst, bufC, E);
    gemm_kernel<128, true><<<gblocks, blk, 0, stream>>>(x, bufC, Ws[0], Wn[0], bn[0], bufA, N);

    // ---- layer 1 (input = bufA)
    gemm_kernel<128, false><<<gblocks, blk, 0, stream>>>(bufA, nullptr, Wp[1], nullptr, bp[1], bufB, N);
    zero_kernel<<<zblocks, blk, 0, stream>>>((float4*)bufC, n4);
    scatter_max_kernel<<<2048, blk, 0, stream>>>(bufB, esrc, edst, bufC, E);
    gemm_kernel<128, true><<<gblocks, blk, 0, stream>>>(bufA, bufC, Ws[1], Wn[1], bn[1], bufB, N);

    // ---- layer 2 (input = bufB, DO=64)
    gemm_kernel<128, false><<<gblocks, blk, 0, stream>>>(bufB, nullptr, Wp[2], nullptr, bp[2], bufA, N);
    zero_kernel<<<zblocks, blk, 0, stream>>>((float4*)bufC, n4);
    scatter_max_kernel<<<2048, blk, 0, stream>>>(bufA, esrc, edst, bufC, E);
    gemm_kernel<64, true><<<gblocks, blk, 0, stream>>>(bufB, bufC, Ws[2], Wn[2], bn[2], bufA, N);

    // ---- log_softmax -> d_out
    logsoftmax_kernel<<<(N + 3) / 4, blk, 0, stream>>>(bufA, (float*)d_out, N);
}

// Round 2
// 768.341 us; speedup vs baseline: 2.6594x; 2.6594x over previous
//
#include <hip/hip_runtime.h>
#include <cstddef>
#include <cstdint>

#define NNODES 100000
#define NEDGES 800000

// ---------------------------------------------------------------------------
// zero-fill (avoids hipMemsetAsync under graph capture)
// ---------------------------------------------------------------------------
__global__ __launch_bounds__(256) void zero_kernel(float4* __restrict__ p, int n4) {
    int i = blockIdx.x * blockDim.x + threadIdx.x;
    const int stride = gridDim.x * blockDim.x;
    for (; i < n4; i += stride) p[i] = make_float4(0.f, 0.f, 0.f, 0.f);
}

// ---------------------------------------------------------------------------
// CSR build: count in-degree, scan, fill column (src) indices.
// ---------------------------------------------------------------------------
__global__ __launch_bounds__(256) void count_kernel(
    const int* __restrict__ dst, int* __restrict__ deg, int E)
{
    int e = blockIdx.x * 256 + threadIdx.x;
    if (e < E) atomicAdd(&deg[dst[e]], 1);
}

// block scans 1024 elements (256 threads x 4); writes per-element exclusive
// prefix (within block) to rowptr and block total to bsum.
__global__ __launch_bounds__(256) void scan_blocks_kernel(
    const int* __restrict__ deg, int* __restrict__ rowptr,
    int* __restrict__ bsum, int N)
{
    __shared__ int sdata[256];
    const int tid = threadIdx.x;
    const int base = blockIdx.x * 1024 + tid * 4;
    int v[4];
    int t = 0;
#pragma unroll
    for (int j = 0; j < 4; ++j) {
        v[j] = (base + j < N) ? deg[base + j] : 0;
        t += v[j];
    }
    sdata[tid] = t;
    __syncthreads();
#pragma unroll
    for (int off = 1; off < 256; off <<= 1) {
        int x = (tid >= off) ? sdata[tid - off] : 0;
        __syncthreads();
        if (tid >= off) sdata[tid] += x;
        __syncthreads();
    }
    int run = sdata[tid] - t;   // exclusive prefix of this thread's chunk
    if (tid == 255) bsum[blockIdx.x] = sdata[255];
#pragma unroll
    for (int j = 0; j < 4; ++j) {
        if (base + j < N) rowptr[base + j] = run;
        run += v[j];
    }
}

// single block: exclusive scan of block sums (NB <= 128)
__global__ __launch_bounds__(128) void scan_bsum_kernel(int* __restrict__ bsum, int NB)
{
    __shared__ int sdata[128];
    const int tid = threadIdx.x;
    int t = (tid < NB) ? bsum[tid] : 0;
    sdata[tid] = t;
    __syncthreads();
#pragma unroll
    for (int off = 1; off < 128; off <<= 1) {
        int x = (tid >= off) ? sdata[tid - off] : 0;
        __syncthreads();
        if (tid >= off) sdata[tid] += x;
        __syncthreads();
    }
    if (tid < NB) bsum[tid] = sdata[tid] - t;   // exclusive
}

__global__ __launch_bounds__(256) void scan_add_kernel(
    int* __restrict__ rowptr, const int* __restrict__ bsum, int N, int E)
{
    int i = blockIdx.x * 256 + threadIdx.x;
    if (i < N) rowptr[i] += bsum[i >> 10];
    if (i == 0) rowptr[N] = E;
}

// consumes deg (counts -> 0); col order within a node is arbitrary (max is
// order-independent, bitwise deterministic: finite floats only)
__global__ __launch_bounds__(256) void fill_kernel(
    const int* __restrict__ src, const int* __restrict__ dst,
    const int* __restrict__ rowptr, int* __restrict__ deg,
    int* __restrict__ col, int E)
{
    int e = blockIdx.x * 256 + threadIdx.x;
    if (e < E) {
        const int d = dst[e];
        const int r = atomicSub(&deg[d], 1);
        col[rowptr[d] + r - 1] = src[e];
    }
}

// ---------------------------------------------------------------------------
// gather-max: one wave per dst node, lane holds 2 of 128 features.
// agg[n] = max over in-edges of m[src] (0 if no edges) — no atomics.
// ---------------------------------------------------------------------------
__global__ __launch_bounds__(256) void aggregate_kernel(
    const float* __restrict__ m,
    const int* __restrict__ rowptr,
    const int* __restrict__ col,
    float* __restrict__ agg, int N)
{
    const int lane = threadIdx.x & 63;
    const int node = blockIdx.x * 4 + (threadIdx.x >> 6);
    if (node >= N) return;
    const int beg = rowptr[node];
    const int end = rowptr[node + 1];
    float ax = 0.f, ay = 0.f;
    int e = beg;
    for (; e + 2 <= end; e += 2) {
        const int s0 = col[e];
        const int s1 = col[e + 1];
        const float2 v0 = *(const float2*)&m[(size_t)s0 * 128 + lane * 2];
        const float2 v1 = *(const float2*)&m[(size_t)s1 * 128 + lane * 2];
        ax = fmaxf(ax, fmaxf(v0.x, v1.x));
        ay = fmaxf(ay, fmaxf(v0.y, v1.y));
    }
    if (e < end) {
        const int s0 = col[e];
        const float2 v0 = *(const float2*)&m[(size_t)s0 * 128 + lane * 2];
        ax = fmaxf(ax, v0.x);
        ay = fmaxf(ay, v0.y);
    }
    *(float2*)&agg[(size_t)node * 128 + lane * 2] = make_float2(ax, ay);
}

// ---------------------------------------------------------------------------
// out[N,DO] = relu( A@WA (+ B@WB) + bias )   K=128 fixed
// block = 256 threads as 16(ty) x 16(tx); each thread: 4 rows x (DO/16) cols
// ---------------------------------------------------------------------------
template<int DO, bool DUAL>
__global__ __launch_bounds__(256) void gemm_kernel(
    const float* __restrict__ A,
    const float* __restrict__ B,
    const float* __restrict__ WA,
    const float* __restrict__ WB,
    const float* __restrict__ bias,
    float* __restrict__ out,
    int N)
{
    constexpr int CPT = DO / 16;       // cols per thread (8 or 4)
    constexpr int KCHUNK = 32;
    constexpr int NW = DUAL ? 2 : 1;
    __shared__ float sW[NW * KCHUNK * DO];

    const int tid = threadIdx.x;
    const int tx = tid & 15;
    const int ty = tid >> 4;
    const int row0 = blockIdx.x * 64 + ty * 4;

    float acc[4][CPT];
#pragma unroll
    for (int r = 0; r < 4; ++r)
#pragma unroll
        for (int c = 0; c < CPT; ++c) acc[r][c] = 0.f;

    int rowc[4];
#pragma unroll
    for (int r = 0; r < 4; ++r) rowc[r] = min(row0 + r, N - 1);

    for (int k0 = 0; k0 < 128; k0 += KCHUNK) {
        const int total = KCHUNK * DO;
        for (int i = tid * 4; i < total; i += 256 * 4) {
            *(float4*)&sW[i] = *(const float4*)&WA[k0 * DO + i];
            if constexpr (DUAL)
                *(float4*)&sW[KCHUNK * DO + i] = *(const float4*)&WB[k0 * DO + i];
        }
        __syncthreads();

#pragma unroll 2
        for (int kk = 0; kk < KCHUNK; kk += 4) {
            float4 av[4], bv[4];
#pragma unroll
            for (int r = 0; r < 4; ++r) {
                av[r] = *(const float4*)&A[(size_t)rowc[r] * 128 + k0 + kk];
                if constexpr (DUAL)
                    bv[r] = *(const float4*)&B[(size_t)rowc[r] * 128 + k0 + kk];
            }
#pragma unroll
            for (int j = 0; j < 4; ++j) {
                float wa[CPT];
#pragma unroll
                for (int c = 0; c < CPT; c += 4) {
                    float4 w4 = *(const float4*)&sW[(kk + j) * DO + tx * CPT + c];
                    wa[c] = w4.x; wa[c + 1] = w4.y; wa[c + 2] = w4.z; wa[c + 3] = w4.w;
                }
#pragma unroll
                for (int r = 0; r < 4; ++r) {
                    const float a = (j == 0) ? av[r].x : (j == 1) ? av[r].y
                                  : (j == 2) ? av[r].z : av[r].w;
#pragma unroll
                    for (int c = 0; c < CPT; ++c) acc[r][c] += a * wa[c];
                }
                if constexpr (DUAL) {
                    float wb[CPT];
#pragma unroll
                    for (int c = 0; c < CPT; c += 4) {
                        float4 w4 = *(const float4*)&sW[KCHUNK * DO + (kk + j) * DO + tx * CPT + c];
                        wb[c] = w4.x; wb[c + 1] = w4.y; wb[c + 2] = w4.z; wb[c + 3] = w4.w;
                    }
#pragma unroll
                    for (int r = 0; r < 4; ++r) {
                        const float b = (j == 0) ? bv[r].x : (j == 1) ? bv[r].y
                                      : (j == 2) ? bv[r].z : bv[r].w;
#pragma unroll
                        for (int c = 0; c < CPT; ++c) acc[r][c] += b * wb[c];
                    }
                }
            }
        }
        __syncthreads();
    }

#pragma unroll
    for (int r = 0; r < 4; ++r) {
        const int row = row0 + r;
        if (row < N) {
#pragma unroll
            for (int c = 0; c < CPT; c += 4) {
                float4 o;
                o.x = fmaxf(acc[r][c + 0] + bias[tx * CPT + c + 0], 0.f);
                o.y = fmaxf(acc[r][c + 1] + bias[tx * CPT + c + 1], 0.f);
                o.z = fmaxf(acc[r][c + 2] + bias[tx * CPT + c + 2], 0.f);
                o.w = fmaxf(acc[r][c + 3] + bias[tx * CPT + c + 3], 0.f);
                *(float4*)&out[(size_t)row * DO + tx * CPT + c] = o;
            }
        }
    }
}

// ---------------------------------------------------------------------------
// row-wise log_softmax over 64 classes: one wave per row, lane = col.
// ---------------------------------------------------------------------------
__global__ __launch_bounds__(256) void logsoftmax_kernel(
    const float* __restrict__ in, float* __restrict__ out, int N)
{
    const int lane = threadIdx.x & 63;
    const int row = blockIdx.x * 4 + (threadIdx.x >> 6);
    if (row >= N) return;
    float v = in[(size_t)row * 64 + lane];
    float mx = v;
#pragma unroll
    for (int off = 32; off > 0; off >>= 1) mx = fmaxf(mx, __shfl_xor(mx, off));
    float e = __expf(v - mx);
    float s = e;
#pragma unroll
    for (int off = 32; off > 0; off >>= 1) s += __shfl_xor(s, off);
    out[(size_t)row * 64 + lane] = v - mx - __logf(s);
}

// ---------------------------------------------------------------------------
extern "C" void kernel_launch(void* const* d_in, const int* in_sizes, int n_in,
                              void* d_out, int out_size, void* d_ws, size_t ws_size,
                              hipStream_t stream)
{
    const int N = NNODES, E = NEDGES;
    const float* x  = (const float*)d_in[0];
    const int* esrc = (const int*)d_in[1];
    const int* edst = (const int*)d_in[2];
    const float* Wp[3] = {(const float*)d_in[3], (const float*)d_in[8],  (const float*)d_in[13]};
    const float* bp[3] = {(const float*)d_in[4], (const float*)d_in[9],  (const float*)d_in[14]};
    const float* Ws[3] = {(const float*)d_in[5], (const float*)d_in[10], (const float*)d_in[15]};
    const float* Wn[3] = {(const float*)d_in[6], (const float*)d_in[11], (const float*)d_in[16]};
    const float* bn[3] = {(const float*)d_in[7], (const float*)d_in[12], (const float*)d_in[17]};

    // node feature ping-pong buffers in d_ws (same 153.6 MB layout as R1)
    float* bufA = (float*)d_ws;                 // N*128 f32
    float* bufB = bufA + (size_t)N * 128;       // N*128 f32 (m = pool output)
    float* bufC = bufB + (size_t)N * 128;       // N*128 f32 (agg)

    // CSR scratch lives in d_out's first ~4 MB (25.6 MB total); it is dead by
    // the time the final log_softmax overwrites d_out.
    int* deg    = (int*)d_out;                  // N ints
    int* rowptr = deg + N;                      // N+1 ints (padded to N+4)
    int* col    = rowptr + N + 4;               // E ints
    int* bsum   = col + E;                      // 128 ints

    const int gblocks = (N + 63) / 64;          // 1563
    const int eblocks = (E + 255) / 256;        // 3125
    const int nb1024  = (N + 1023) / 1024;      // 98
    dim3 blk(256);

    // ---- CSR build (once per call, shared by all 3 layers)
    zero_kernel<<<128, blk, 0, stream>>>((float4*)deg, N / 4);
    count_kernel<<<eblocks, blk, 0, stream>>>(edst, deg, E);
    scan_blocks_kernel<<<nb1024, blk, 0, stream>>>(deg, rowptr, bsum, N);
    scan_bsum_kernel<<<1, 128, 0, stream>>>(bsum, nb1024);
    scan_add_kernel<<<(N + 255) / 256, blk, 0, stream>>>(rowptr, bsum, N, E);
    fill_kernel<<<eblocks, blk, 0, stream>>>(esrc, edst, rowptr, deg, col, E);

    const int ablocks = (N + 3) / 4;            // 25000 (1 wave per node)

    // ---- layer 0 (input = x)
    gemm_kernel<128, false><<<gblocks, blk, 0, stream>>>(x, nullptr, Wp[0], nullptr, bp[0], bufB, N);
    aggregate_kernel<<<ablocks, blk, 0, stream>>>(bufB, rowptr, col, bufC, N);
    gemm_kernel<128, true><<<gblocks, blk, 0, stream>>>(x, bufC, Ws[0], Wn[0], bn[0], bufA, N);

    // ---- layer 1 (input = bufA)
    gemm_kernel<128, false><<<gblocks, blk, 0, stream>>>(bufA, nullptr, Wp[1], nullptr, bp[1], bufB, N);
    aggregate_kernel<<<ablocks, blk, 0, stream>>>(bufB, rowptr, col, bufC, N);
    gemm_kernel<128, true><<<gblocks, blk, 0, stream>>>(bufA, bufC, Ws[1], Wn[1], bn[1], bufB, N);

    // ---- layer 2 (input = bufB, DO=64)
    gemm_kernel<128, false><<<gblocks, blk, 0, stream>>>(bufB, nullptr, Wp[2], nullptr, bp[2], bufA, N);
    aggregate_kernel<<<ablocks, blk, 0, stream>>>(bufA, rowptr, col, bufC, N);
    gemm_kernel<64, true><<<gblocks, blk, 0, stream>>>(bufB, bufC, Ws[2], Wn[2], bn[2], bufA, N);

    // ---- log_softmax -> d_out (overwrites CSR scratch; that's fine, it's dead)
    logsoftmax_kernel<<<(N + 3) / 4, blk, 0, stream>>>(bufA, (float*)d_out, N);
}

// Round 3
// 696.571 us; speedup vs baseline: 2.9334x; 1.1030x over previous
//
#include <hip/hip_runtime.h>
#include <cstddef>
#include <cstdint>

#define NNODES 100000
#define NEDGES 800000

typedef unsigned short u16;
typedef __attribute__((ext_vector_type(8))) short short8;  // 8 x bf16 (4 VGPRs)
typedef __attribute__((ext_vector_type(4))) float f32x4;

__device__ __forceinline__ u16 f32_to_bf16(float f) {
    union { float f; uint32_t u; } v; v.f = f;
    uint32_t r = v.u + 0x7FFF + ((v.u >> 16) & 1);   // RNE; inputs finite
    return (u16)(r >> 16);
}
__device__ __forceinline__ float bf16_to_f32(u16 h) {
    union { uint32_t u; float f; } v; v.u = ((uint32_t)h) << 16;
    return v.f;
}

// ---------------------------------------------------------------------------
// zero-fill (avoids hipMemsetAsync under graph capture)
// ---------------------------------------------------------------------------
__global__ __launch_bounds__(256) void zero_kernel(float4* __restrict__ p, int n4) {
    int i = blockIdx.x * blockDim.x + threadIdx.x;
    const int stride = gridDim.x * blockDim.x;
    for (; i < n4; i += stride) p[i] = make_float4(0.f, 0.f, 0.f, 0.f);
}

// ---------------------------------------------------------------------------
// CSR build: count in-degree, scan, fill column (src) indices.  (same as R2)
// ---------------------------------------------------------------------------
__global__ __launch_bounds__(256) void count_kernel(
    const int* __restrict__ dst, int* __restrict__ deg, int E)
{
    int e = blockIdx.x * 256 + threadIdx.x;
    if (e < E) atomicAdd(&deg[dst[e]], 1);
}

__global__ __launch_bounds__(256) void scan_blocks_kernel(
    const int* __restrict__ deg, int* __restrict__ rowptr,
    int* __restrict__ bsum, int N)
{
    __shared__ int sdata[256];
    const int tid = threadIdx.x;
    const int base = blockIdx.x * 1024 + tid * 4;
    int v[4];
    int t = 0;
#pragma unroll
    for (int j = 0; j < 4; ++j) {
        v[j] = (base + j < N) ? deg[base + j] : 0;
        t += v[j];
    }
    sdata[tid] = t;
    __syncthreads();
#pragma unroll
    for (int off = 1; off < 256; off <<= 1) {
        int x = (tid >= off) ? sdata[tid - off] : 0;
        __syncthreads();
        if (tid >= off) sdata[tid] += x;
        __syncthreads();
    }
    int run = sdata[tid] - t;
    if (tid == 255) bsum[blockIdx.x] = sdata[255];
#pragma unroll
    for (int j = 0; j < 4; ++j) {
        if (base + j < N) rowptr[base + j] = run;
        run += v[j];
    }
}

__global__ __launch_bounds__(128) void scan_bsum_kernel(int* __restrict__ bsum, int NB)
{
    __shared__ int sdata[128];
    const int tid = threadIdx.x;
    int t = (tid < NB) ? bsum[tid] : 0;
    sdata[tid] = t;
    __syncthreads();
#pragma unroll
    for (int off = 1; off < 128; off <<= 1) {
        int x = (tid >= off) ? sdata[tid - off] : 0;
        __syncthreads();
        if (tid >= off) sdata[tid] += x;
        __syncthreads();
    }
    if (tid < NB) bsum[tid] = sdata[tid] - t;
}

__global__ __launch_bounds__(256) void scan_add_kernel(
    int* __restrict__ rowptr, const int* __restrict__ bsum, int N, int E)
{
    int i = blockIdx.x * 256 + threadIdx.x;
    if (i < N) rowptr[i] += bsum[i >> 10];
    if (i == 0) rowptr[N] = E;
}

__global__ __launch_bounds__(256) void fill_kernel(
    const int* __restrict__ src, const int* __restrict__ dst,
    const int* __restrict__ rowptr, int* __restrict__ deg,
    int* __restrict__ col, int E)
{
    int e = blockIdx.x * 256 + threadIdx.x;
    if (e < E) {
        const int d = dst[e];
        const int r = atomicSub(&deg[d], 1);
        col[rowptr[d] + r - 1] = src[e];
    }
}

// ---------------------------------------------------------------------------
// split f32 -> (hi, lo) bf16 planes. n4 = count/4.
// ---------------------------------------------------------------------------
__global__ __launch_bounds__(256) void split_f32_kernel(
    const float4* __restrict__ in, uint2* __restrict__ hi, uint2* __restrict__ lo, int n4)
{
    int i = blockIdx.x * 256 + threadIdx.x;
    const int stride = gridDim.x * 256;
    for (; i < n4; i += stride) {
        float4 v = in[i];
        u16 h0 = f32_to_bf16(v.x), h1 = f32_to_bf16(v.y);
        u16 h2 = f32_to_bf16(v.z), h3 = f32_to_bf16(v.w);
        u16 l0 = f32_to_bf16(v.x - bf16_to_f32(h0));
        u16 l1 = f32_to_bf16(v.y - bf16_to_f32(h1));
        u16 l2 = f32_to_bf16(v.z - bf16_to_f32(h2));
        u16 l3 = f32_to_bf16(v.w - bf16_to_f32(h3));
        hi[i] = make_uint2((uint32_t)h0 | ((uint32_t)h1 << 16), (uint32_t)h2 | ((uint32_t)h3 << 16));
        lo[i] = make_uint2((uint32_t)l0 | ((uint32_t)l1 << 16), (uint32_t)l2 | ((uint32_t)l3 << 16));
    }
}

// ---------------------------------------------------------------------------
// split + transpose all 9 weight matrices: W[K=128][DO] f32 -> WT_hi/lo[DO][128]
// per matrix: hi plane (16384 u16) then lo plane, at wbase + widx*32768.
// widx 0..6: DO=128 (Wp0,Ws0,Wn0,Wp1,Ws1,Wn1,Wp2); 7,8: DO=64 (Ws2,Wn2).
// ---------------------------------------------------------------------------
struct WPtrs { const float* w[9]; };

__global__ __launch_bounds__(256) void split_weights_kernel(WPtrs p, u16* __restrict__ wbase)
{
    const int idx = blockIdx.x * 256 + threadIdx.x;   // element within matrix
    const int w = blockIdx.y;
    const int DO_ = (w >= 7) ? 64 : 128;
    if (idx >= 128 * DO_) return;
    const float v = p.w[w][idx];
    const int k = idx / DO_;
    const int c = idx - k * DO_;
    u16* hi = wbase + w * 32768;
    u16* lo = hi + 16384;
    const u16 h = f32_to_bf16(v);
    hi[c * 128 + k] = h;
    lo[c * 128 + k] = f32_to_bf16(v - bf16_to_f32(h));
}

// ---------------------------------------------------------------------------
// bf16x3 MFMA GEMM:  out[N,DO] = relu( A@Wa (+ C@Wb) + bias )
// A,C given as hi/lo bf16 planes [N][128]; W as transposed hi/lo [DO][128].
// No LDS: W is L2-resident; A streamed. block = 4 waves; wave = 32 rows
// (2 M-tiles of 16); each wave computes all DO columns for its rows.
// SPLIT_OUT: write hi/lo bf16 planes; else f32 buffer.
// ---------------------------------------------------------------------------
template<int DO, bool DUAL, bool SPLIT_OUT>
__global__ __launch_bounds__(256) void mfma_gemm_kernel(
    const u16* __restrict__ Ahi, const u16* __restrict__ Alo,
    const u16* __restrict__ Chi, const u16* __restrict__ Clo,
    const u16* __restrict__ WaHi, const u16* __restrict__ WaLo,
    const u16* __restrict__ WbHi, const u16* __restrict__ WbLo,
    const float* __restrict__ bias,
    float* __restrict__ outF, u16* __restrict__ outHi, u16* __restrict__ outLo,
    int N)
{
    constexpr int CT = DO / 16;                 // col tiles (8 or 4)
    const int lane = threadIdx.x & 63;
    const int wid  = threadIdx.x >> 6;
    const int l15  = lane & 15;
    const int lk   = (lane >> 4) << 3;          // 0,8,16,24
    const int row0 = (blockIdx.x * 4 + wid) * 32;

    f32x4 acc[2][CT];
#pragma unroll
    for (int m = 0; m < 2; ++m)
#pragma unroll
        for (int c = 0; c < CT; ++c) acc[m][c] = (f32x4){0.f, 0.f, 0.f, 0.f};

    int aoff0, aoff1;
    {
        int r0 = row0 + l15;      if (r0 > N - 1) r0 = N - 1;
        int r1 = row0 + 16 + l15; if (r1 > N - 1) r1 = N - 1;
        aoff0 = r0 * 128 + lk;
        aoff1 = r1 * 128 + lk;
    }
    const int woff = l15 * 128 + lk;

    for (int k0 = 0; k0 < 128; k0 += 32) {
        // ---- H path
        {
            short8 ah0 = *(const short8*)(Ahi + aoff0 + k0);
            short8 ah1 = *(const short8*)(Ahi + aoff1 + k0);
            short8 al0 = *(const short8*)(Alo + aoff0 + k0);
            short8 al1 = *(const short8*)(Alo + aoff1 + k0);
#pragma unroll
            for (int ct = 0; ct < CT; ++ct) {
                short8 wh = *(const short8*)(WaHi + ct * (16 * 128) + woff + k0);
                short8 wl = *(const short8*)(WaLo + ct * (16 * 128) + woff + k0);
                acc[0][ct] = __builtin_amdgcn_mfma_f32_16x16x32_bf16(ah0, wh, acc[0][ct], 0, 0, 0);
                acc[1][ct] = __builtin_amdgcn_mfma_f32_16x16x32_bf16(ah1, wh, acc[1][ct], 0, 0, 0);
                acc[0][ct] = __builtin_amdgcn_mfma_f32_16x16x32_bf16(al0, wh, acc[0][ct], 0, 0, 0);
                acc[1][ct] = __builtin_amdgcn_mfma_f32_16x16x32_bf16(al1, wh, acc[1][ct], 0, 0, 0);
                acc[0][ct] = __builtin_amdgcn_mfma_f32_16x16x32_bf16(ah0, wl, acc[0][ct], 0, 0, 0);
                acc[1][ct] = __builtin_amdgcn_mfma_f32_16x16x32_bf16(ah1, wl, acc[1][ct], 0, 0, 0);
            }
        }
        // ---- neighbor path
        if constexpr (DUAL) {
            short8 bh0 = *(const short8*)(Chi + aoff0 + k0);
            short8 bh1 = *(const short8*)(Chi + aoff1 + k0);
            short8 bl0 = *(const short8*)(Clo + aoff0 + k0);
            short8 bl1 = *(const short8*)(Clo + aoff1 + k0);
#pragma unroll
            for (int ct = 0; ct < CT; ++ct) {
                short8 wh = *(const short8*)(WbHi + ct * (16 * 128) + woff + k0);
                short8 wl = *(const short8*)(WbLo + ct * (16 * 128) + woff + k0);
                acc[0][ct] = __builtin_amdgcn_mfma_f32_16x16x32_bf16(bh0, wh, acc[0][ct], 0, 0, 0);
                acc[1][ct] = __builtin_amdgcn_mfma_f32_16x16x32_bf16(bh1, wh, acc[1][ct], 0, 0, 0);
                acc[0][ct] = __builtin_amdgcn_mfma_f32_16x16x32_bf16(bl0, wh, acc[0][ct], 0, 0, 0);
                acc[1][ct] = __builtin_amdgcn_mfma_f32_16x16x32_bf16(bl1, wh, acc[1][ct], 0, 0, 0);
                acc[0][ct] = __builtin_amdgcn_mfma_f32_16x16x32_bf16(bh0, wl, acc[0][ct], 0, 0, 0);
                acc[1][ct] = __builtin_amdgcn_mfma_f32_16x16x32_bf16(bh1, wl, acc[1][ct], 0, 0, 0);
            }
        }
    }

    // ---- epilogue: D frag row = (lane>>4)*4 + j, col = l15 (per m89 layout)
    float bv[CT];
#pragma unroll
    for (int ct = 0; ct < CT; ++ct) bv[ct] = bias[ct * 16 + l15];

    const int jrow = (lane >> 4) << 2;
#pragma unroll
    for (int m = 0; m < 2; ++m) {
#pragma unroll
        for (int j = 0; j < 4; ++j) {
            const int r = row0 + m * 16 + jrow + j;
            if (r < N) {
#pragma unroll
                for (int ct = 0; ct < CT; ++ct) {
                    float v = fmaxf(acc[m][ct][j] + bv[ct], 0.f);
                    const size_t o = (size_t)r * DO + ct * 16 + l15;
                    if constexpr (SPLIT_OUT) {
                        const u16 h = f32_to_bf16(v);
                        outHi[o] = h;
                        outLo[o] = f32_to_bf16(v - bf16_to_f32(h));
                    } else {
                        outF[o] = v;
                    }
                }
            }
        }
    }
}

// ---------------------------------------------------------------------------
// gather-max over in-edges (m is f32 [N][128]); writes agg hi/lo bf16 planes.
// ---------------------------------------------------------------------------
__global__ __launch_bounds__(256) void aggregate_split_kernel(
    const float* __restrict__ m,
    const int* __restrict__ rowptr,
    const int* __restrict__ col,
    u16* __restrict__ aggHi, u16* __restrict__ aggLo, int N)
{
    const int lane = threadIdx.x & 63;
    const int node = blockIdx.x * 4 + (threadIdx.x >> 6);
    if (node >= N) return;
    const int beg = rowptr[node];
    const int end = rowptr[node + 1];
    float ax = 0.f, ay = 0.f;
    int e = beg;
    for (; e + 2 <= end; e += 2) {
        const int s0 = col[e];
        const int s1 = col[e + 1];
        const float2 v0 = *(const float2*)&m[(size_t)s0 * 128 + lane * 2];
        const float2 v1 = *(const float2*)&m[(size_t)s1 * 128 + lane * 2];
        ax = fmaxf(ax, fmaxf(v0.x, v1.x));
        ay = fmaxf(ay, fmaxf(v0.y, v1.y));
    }
    if (e < end) {
        const float2 v0 = *(const float2*)&m[(size_t)col[e] * 128 + lane * 2];
        ax = fmaxf(ax, v0.x);
        ay = fmaxf(ay, v0.y);
    }
    const u16 hx = f32_to_bf16(ax), hy = f32_to_bf16(ay);
    const u16 lx = f32_to_bf16(ax - bf16_to_f32(hx));
    const u16 ly = f32_to_bf16(ay - bf16_to_f32(hy));
    const size_t o = (size_t)node * 128 + lane * 2;
    *(uint32_t*)(aggHi + o) = (uint32_t)hx | ((uint32_t)hy << 16);
    *(uint32_t*)(aggLo + o) = (uint32_t)lx | ((uint32_t)ly << 16);
}

// ---------------------------------------------------------------------------
// row-wise log_softmax over 64 classes: one wave per row, lane = col.
// ---------------------------------------------------------------------------
__global__ __launch_bounds__(256) void logsoftmax_kernel(
    const float* __restrict__ in, float* __restrict__ out, int N)
{
    const int lane = threadIdx.x & 63;
    const int row = blockIdx.x * 4 + (threadIdx.x >> 6);
    if (row >= N) return;
    float v = in[(size_t)row * 64 + lane];
    float mx = v;
#pragma unroll
    for (int off = 32; off > 0; off >>= 1) mx = fmaxf(mx, __shfl_xor(mx, off));
    float e = __expf(v - mx);
    float s = e;
#pragma unroll
    for (int off = 32; off > 0; off >>= 1) s += __shfl_xor(s, off);
    out[(size_t)row * 64 + lane] = v - mx - __logf(s);
}

// ---------------------------------------------------------------------------
extern "C" void kernel_launch(void* const* d_in, const int* in_sizes, int n_in,
                              void* d_out, int out_size, void* d_ws, size_t ws_size,
                              hipStream_t stream)
{
    const int N = NNODES, E = NEDGES;
    const float* x  = (const float*)d_in[0];
    const int* esrc = (const int*)d_in[1];
    const int* edst = (const int*)d_in[2];
    const float* bp[3] = {(const float*)d_in[4], (const float*)d_in[9],  (const float*)d_in[14]};
    const float* bn[3] = {(const float*)d_in[7], (const float*)d_in[12], (const float*)d_in[17]};

    // bf16 planes in d_ws: 6 planes of N*128*2 = 25.6 MB (153.6 MB total, as R2)
    char* ws = (char*)d_ws;
    const size_t P = (size_t)N * 128 * 2;
    u16* p0 = (u16*)(ws);
    u16* p1 = (u16*)(ws + P);
    u16* p2 = (u16*)(ws + 2 * P);
    u16* p3 = (u16*)(ws + 3 * P);
    u16* p4 = (u16*)(ws + 4 * P);        // agg hi
    u16* p5 = (u16*)(ws + 5 * P);        // agg lo
    float* m01 = (float*)(ws);           // f32 m spanning planes 0,1
    float* m23 = (float*)(ws + 2 * P);   // f32 m spanning planes 2,3
    float* logits = (float*)(ws + 2 * P);// f32 [N][64] (one plane)

    // CSR + split weights live in d_out (first ~5 MB of 25.6 MB); dead before
    // the final log_softmax overwrites d_out.
    int* deg    = (int*)d_out;
    int* rowptr = deg + N;
    int* col    = rowptr + N + 4;
    int* bsum   = col + E;
    u16* wbase  = (u16*)((int*)d_out + (1 << 20));   // 4 MB offset
    auto WHI = [&](int i) { return wbase + i * 32768; };
    auto WLO = [&](int i) { return wbase + i * 32768 + 16384; };

    const int eblocks = (E + 255) / 256;
    const int nb1024  = (N + 1023) / 1024;
    const int gblocks = (N + 127) / 128;     // 782
    const int ablocks = (N + 3) / 4;         // 25000
    dim3 blk(256);

    // ---- CSR build
    zero_kernel<<<128, blk, 0, stream>>>((float4*)deg, N / 4);
    count_kernel<<<eblocks, blk, 0, stream>>>(edst, deg, E);
    scan_blocks_kernel<<<nb1024, blk, 0, stream>>>(deg, rowptr, bsum, N);
    scan_bsum_kernel<<<1, 128, 0, stream>>>(bsum, nb1024);
    scan_add_kernel<<<(N + 255) / 256, blk, 0, stream>>>(rowptr, bsum, N, E);
    fill_kernel<<<eblocks, blk, 0, stream>>>(esrc, edst, rowptr, deg, col, E);

    // ---- weight split+transpose (9 matrices), x split
    WPtrs wp;
    wp.w[0] = (const float*)d_in[3];  wp.w[1] = (const float*)d_in[5];  wp.w[2] = (const float*)d_in[6];
    wp.w[3] = (const float*)d_in[8];  wp.w[4] = (const float*)d_in[10]; wp.w[5] = (const float*)d_in[11];
    wp.w[6] = (const float*)d_in[13]; wp.w[7] = (const float*)d_in[15]; wp.w[8] = (const float*)d_in[16];
    split_weights_kernel<<<dim3(64, 9), blk, 0, stream>>>(wp, wbase);
    split_f32_kernel<<<2048, blk, 0, stream>>>((const float4*)x, (uint2*)p0, (uint2*)p1, N * 128 / 4);

    // ---- layer 0: H = (p0,p1)
    mfma_gemm_kernel<128, false, false><<<gblocks, blk, 0, stream>>>(
        p0, p1, nullptr, nullptr, WHI(0), WLO(0), nullptr, nullptr, bp[0], m23, nullptr, nullptr, N);
    aggregate_split_kernel<<<ablocks, blk, 0, stream>>>(m23, rowptr, col, p4, p5, N);
    mfma_gemm_kernel<128, true, true><<<gblocks, blk, 0, stream>>>(
        p0, p1, p4, p5, WHI(1), WLO(1), WHI(2), WLO(2), bn[0], nullptr, p2, p3, N);

    // ---- layer 1: H = (p2,p3)
    mfma_gemm_kernel<128, false, false><<<gblocks, blk, 0, stream>>>(
        p2, p3, nullptr, nullptr, WHI(3), WLO(3), nullptr, nullptr, bp[1], m01, nullptr, nullptr, N);
    aggregate_split_kernel<<<ablocks, blk, 0, stream>>>(m01, rowptr, col, p4, p5, N);
    mfma_gemm_kernel<128, true, true><<<gblocks, blk, 0, stream>>>(
        p2, p3, p4, p5, WHI(4), WLO(4), WHI(5), WLO(5), bn[1], nullptr, p0, p1, N);

    // ---- layer 2: H = (p0,p1), DO=64
    mfma_gemm_kernel<128, false, false><<<gblocks, blk, 0, stream>>>(
        p0, p1, nullptr, nullptr, WHI(6), WLO(6), nullptr, nullptr, bp[2], m23, nullptr, nullptr, N);
    aggregate_split_kernel<<<ablocks, blk, 0, stream>>>(m23, rowptr, col, p4, p5, N);
    mfma_gemm_kernel<64, true, false><<<gblocks, blk, 0, stream>>>(
        p0, p1, p4, p5, WHI(7), WLO(7), WHI(8), WLO(8), bn[2], logits, nullptr, nullptr, N);

    // ---- log_softmax -> d_out
    logsoftmax_kernel<<<ablocks, blk, 0, stream>>>(logits, (float*)d_out, N);
}